// Round 1
// baseline (783.608 us; speedup 1.0000x reference)
//
#include <hip/hip_runtime.h>
#include <hip/hip_bf16.h>
#include <math.h>

#define N_NODES 100000
#define N_EDGES 1600000
#define IN_DIM  768
#define HIDDEN  256

#define SCAN_B  256
#define N_SBLK  ((N_NODES + SCAN_B - 1) / SCAN_B)   // 391

// ---- ws layout (bytes), all offsets 16B-aligned ----
#define H_OFF    0ull                  // bf16 h' [N_NODES][HIDDEN]     51,200,000 B
#define ADJ_OFF  51200000ull           // int adj [N_EDGES]              6,400,000 B
#define RS_OFF   57600000ull           // int row_start [N_NODES+1]        400,004 B
#define CUR_OFF  58000016ull           // int cursor [N_NODES]             400,000 B
#define DEG_OFF  58400016ull           // int deg [N_NODES]                400,000 B
#define DINV_OFF 58800016ull           // float dinv [N_NODES]             400,000 B
#define W1T_OFF  59200016ull           // bf16 W1t [HIDDEN][IN_DIM]        393,216 B
#define BSUM_OFF 59593232ull           // int bsum [N_SBLK]                  1,564 B
// total ~59.6 MB

typedef short          bf16x8 __attribute__((ext_vector_type(8)));
typedef float          fp32x4 __attribute__((ext_vector_type(4)));
typedef unsigned short u16x4  __attribute__((ext_vector_type(4)));

__device__ inline short f2bf(float f) {
    union { float f; unsigned u; } c; c.f = f;
    unsigned u = c.u;
    unsigned r = u + 0x7FFFu + ((u >> 16) & 1u);   // RNE
    return (short)(r >> 16);
}

__device__ inline fp32x4 bf4_to_f4(u16x4 v) {
    fp32x4 r;
    for (int j = 0; j < 4; j++) {
        union { unsigned u; float f; } c;
        c.u = ((unsigned)v[j]) << 16;
        r[j] = c.f;
    }
    return r;
}

// async global->LDS, 16B per lane (wave-uniform dest base + lane*16)
__device__ inline void async16(const void* g, void* l) {
    __builtin_amdgcn_global_load_lds(
        (const __attribute__((address_space(1))) unsigned int*)g,
        (__attribute__((address_space(3))) unsigned int*)l,
        16, 0, 0);
}

// ---------------- init: zero deg + cursor ----------------
__global__ void init_kernel(int* __restrict__ deg, int* __restrict__ cursor) {
    int i = blockIdx.x * blockDim.x + threadIdx.x;
    if (i < N_NODES) { deg[i] = 0; cursor[i] = 0; }
}

// ---------------- W1 -> W1t (bf16, [HIDDEN][IN_DIM]) ----------------
__global__ void w1t_kernel(const float* __restrict__ w1, short* __restrict__ w1t) {
    int i = blockIdx.x * blockDim.x + threadIdx.x;
    if (i < HIDDEN * IN_DIM) {
        int n = i / IN_DIM, k = i % IN_DIM;
        w1t[i] = f2bf(w1[(size_t)k * HIDDEN + n]);
    }
}

// ---------------- count in-degree (real edges only) ----------------
__global__ void count_kernel(const int* __restrict__ dst, int* __restrict__ deg) {
    int e = blockIdx.x * blockDim.x + threadIdx.x;
    if (e < N_EDGES) atomicAdd(&deg[dst[e]], 1);
}

// ---------------- scan phase 1: per-block sums ----------------
__global__ __launch_bounds__(SCAN_B) void scan1_kernel(const int* __restrict__ deg,
                                                       int* __restrict__ bsum) {
    int i = blockIdx.x * SCAN_B + threadIdx.x;
    int v = (i < N_NODES) ? deg[i] : 0;
    for (int off = 32; off > 0; off >>= 1) v += __shfl_down(v, off, 64);
    __shared__ int wsum[SCAN_B / 64];
    int lane = threadIdx.x & 63, w = threadIdx.x >> 6;
    if (lane == 0) wsum[w] = v;
    __syncthreads();
    if (threadIdx.x == 0) {
        int s = 0;
        for (int j = 0; j < SCAN_B / 64; j++) s += wsum[j];
        bsum[blockIdx.x] = s;
    }
}

// ---------------- scan phase 2: exclusive-scan the block sums (1 block) ----------------
__global__ __launch_bounds__(512) void scan2_kernel(int* __restrict__ bsum) {
    __shared__ int s[512];
    int tid = threadIdx.x;
    int v = (tid < N_SBLK) ? bsum[tid] : 0;
    s[tid] = v;
    __syncthreads();
    for (int off = 1; off < 512; off <<= 1) {
        int t = (tid >= off) ? s[tid - off] : 0;
        __syncthreads();
        s[tid] += t;
        __syncthreads();
    }
    if (tid < N_SBLK) bsum[tid] = s[tid] - v;   // exclusive
}

// ---------------- scan phase 3: block-local scan + offset; also dinv ----------------
__global__ __launch_bounds__(SCAN_B) void scan3_kernel(const int* __restrict__ deg,
                                                       const int* __restrict__ bsum,
                                                       int* __restrict__ row_start,
                                                       float* __restrict__ dinv) {
    __shared__ int s[SCAN_B];
    int i = blockIdx.x * SCAN_B + threadIdx.x;
    int tid = threadIdx.x;
    int d = (i < N_NODES) ? deg[i] : 0;
    s[tid] = d;
    __syncthreads();
    for (int off = 1; off < SCAN_B; off <<= 1) {
        int t = (tid >= off) ? s[tid - off] : 0;
        __syncthreads();
        s[tid] += t;
        __syncthreads();
    }
    if (i < N_NODES) {
        row_start[i] = bsum[blockIdx.x] + s[tid] - d;   // exclusive
        dinv[i] = rsqrtf((float)(d + 1));               // +1 self loop
        if (i == N_NODES - 1) row_start[N_NODES] = N_EDGES;  // deg sums to N_EDGES
    }
}

// ---------------- fill CSR adjacency (src list grouped by dst) ----------------
__global__ void fill_kernel(const int* __restrict__ src, const int* __restrict__ dst,
                            const int* __restrict__ row_start, int* __restrict__ cursor,
                            int* __restrict__ adj) {
    int e = blockIdx.x * blockDim.x + threadIdx.x;
    if (e < N_EDGES) {
        int d = dst[e];
        int p = row_start[d] + atomicAdd(&cursor[d], 1);
        adj[p] = src[e];
    }
}

// ---------------- GEMM1: h'[r] = bf16(dinv[r] * (x[r] @ W1)) ----------------
// 128x128 tile, BK=32. global_load_lds (width 16) double-buffered staging:
//   A tile fp32 [128][32] (16 KB), bf16-converted at frag-read time.
//   B tile bf16 [128][32] (8 KB).
// LDS dest is linear (global_load_lds constraint); bank conflicts on the frag
// reads are fixed by XOR-swizzling the 16B slot on BOTH the global source
// address and the LDS read address (rule: both-sides-or-neither):
//   A: slot ^= (row & 7)        (row stride 128 B -> 2-way, free)
//   B: slot ^= ((row >> 1) & 3) (row stride  64 B -> 2-way, free)
// 2-phase schedule: STAGE(next) -> ds_read(cur) -> MFMA -> __syncthreads.
__global__ __launch_bounds__(256) void gemm1_kernel(const float* __restrict__ x,
                                                    const short* __restrict__ w1t,
                                                    const float* __restrict__ dinv,
                                                    unsigned short* __restrict__ h) {
    __shared__ float a_lds[2][128 * 32];   // 2 x 16 KB
    __shared__ short b_lds[2][128 * 32];   // 2 x  8 KB

    const int tid  = threadIdx.x;
    const int lane = tid & 63;
    const int wave = tid >> 6;
    const int wm = (wave >> 1) * 64;
    const int wn = (wave & 1) * 64;
    const int l15 = lane & 15;
    const int q   = lane >> 4;
    const int row0 = blockIdx.x * 128;
    const int col0 = blockIdx.y * 128;

    // ---- staging geometry ----
    // A: 1024 x 16B chunks per tile; wave w issue i covers chunks (w*4+i)*64+lane.
    // dest chunk cd = row*8 + slot; source slot = slot ^ (row & 7).
    const float* ag[4];
    int alo[4];
#pragma unroll
    for (int i = 0; i < 4; i++) {
        int cd = (wave * 4 + i) * 64 + lane;
        int ar = cd >> 3;
        int asrc = (cd & 7) ^ (ar & 7);
        int grow = row0 + ar;
        if (grow >= N_NODES) grow = N_NODES - 1;   // clamp: OOB rows never stored
        ag[i]  = x + (size_t)grow * IN_DIM + asrc * 4;   // +k0 floats at issue
        alo[i] = cd * 16;                                 // byte offset in buffer
    }
    // B: 512 x 16B chunks; wave w issue i covers chunks (w*2+i)*64+lane.
    // dest chunk cd = row*4 + slot; source slot = slot ^ ((row>>1) & 3).
    const short* bg[2];
    int blo[2];
#pragma unroll
    for (int i = 0; i < 2; i++) {
        int cd = (wave * 2 + i) * 64 + lane;
        int br = cd >> 2;
        int bsrc = (cd & 3) ^ ((br >> 1) & 3);
        bg[i]  = w1t + (size_t)(col0 + br) * IN_DIM + bsrc * 8;  // +k0 shorts
        blo[i] = cd * 16;
    }

    fp32x4 acc[4][4];
#pragma unroll
    for (int i = 0; i < 4; i++)
#pragma unroll
        for (int j = 0; j < 4; j++)
#pragma unroll
            for (int r = 0; r < 4; r++) acc[i][j][r] = 0.0f;

#define STAGE(buf, k0) do {                                                   \
        char* ab = (char*)a_lds[buf];                                         \
        char* bb = (char*)b_lds[buf];                                         \
        async16(ag[0] + (k0), ab + alo[0]);                                   \
        async16(ag[1] + (k0), ab + alo[1]);                                   \
        async16(ag[2] + (k0), ab + alo[2]);                                   \
        async16(ag[3] + (k0), ab + alo[3]);                                   \
        async16(bg[0] + (k0), bb + blo[0]);                                   \
        async16(bg[1] + (k0), bb + blo[1]);                                   \
    } while (0)

    STAGE(0, 0);
    __syncthreads();   // vmcnt(0) drain + barrier: tile 0 resident

    int cur = 0;
    for (int k0 = 0; k0 < IN_DIM; k0 += 32) {
        int kn = k0 + 32;
        if (kn < IN_DIM) STAGE(cur ^ 1, kn);   // issue-early: overlaps compute below

        bf16x8 af[4], bfr[4];
#pragma unroll
        for (int mt = 0; mt < 4; mt++) {
            int ar = wm + mt * 16 + l15;
            const float* ap = &a_lds[cur][ar * 32];
            int c0 = (2 * q) ^ (ar & 7);
            fp32x4 f0 = *(const fp32x4*)(ap + (c0 << 2));        // orig slot 2q
            fp32x4 f1 = *(const fp32x4*)(ap + ((c0 ^ 1) << 2));  // orig slot 2q+1
            bf16x8 av;
            av[0] = f2bf(f0[0]); av[1] = f2bf(f0[1]);
            av[2] = f2bf(f0[2]); av[3] = f2bf(f0[3]);
            av[4] = f2bf(f1[0]); av[5] = f2bf(f1[1]);
            av[6] = f2bf(f1[2]); av[7] = f2bf(f1[3]);
            af[mt] = av;
        }
#pragma unroll
        for (int nt = 0; nt < 4; nt++) {
            int br = wn + nt * 16 + l15;
            int bs = q ^ ((br >> 1) & 3);
            bfr[nt] = *(const bf16x8*)(&b_lds[cur][br * 32 + bs * 8]);
        }
#pragma unroll
        for (int mt = 0; mt < 4; mt++)
#pragma unroll
            for (int nt = 0; nt < 4; nt++)
                acc[mt][nt] = __builtin_amdgcn_mfma_f32_16x16x32_bf16(
                    af[mt], bfr[nt], acc[mt][nt], 0, 0, 0);

        __syncthreads();   // drains vmcnt(0): next tile resident; LDS reads done
        cur ^= 1;
    }
#undef STAGE

    // epilogue: h'[row][col] = bf16(dinv[row] * acc)
    float dv[4][4];
#pragma unroll
    for (int mt = 0; mt < 4; mt++)
#pragma unroll
        for (int r = 0; r < 4; r++) {
            int row = row0 + wm + mt * 16 + q * 4 + r;
            dv[mt][r] = (row < N_NODES) ? dinv[row] : 0.0f;
        }
#pragma unroll
    for (int mt = 0; mt < 4; mt++) {
#pragma unroll
        for (int nt = 0; nt < 4; nt++) {
            int col = col0 + wn + nt * 16 + l15;
#pragma unroll
            for (int r = 0; r < 4; r++) {
                int row = row0 + wm + mt * 16 + q * 4 + r;
                if (row < N_NODES)
                    h[(size_t)row * HIDDEN + col] =
                        (unsigned short)f2bf(dv[mt][r] * acc[mt][nt][r]);
            }
        }
    }
}

// ---------------- aggregate + bias + relu + W2 + log_softmax ----------------
// one wave per dst node; lane holds 4 of the 256 hidden channels (bf16 h').
// edge loop unrolled x4 with 4 accumulators -> 4 gathers in flight.
__global__ __launch_bounds__(256) void aggregate_kernel(
    const unsigned short* __restrict__ h, const int* __restrict__ adj,
    const int* __restrict__ row_start, const float* __restrict__ dinv,
    const float* __restrict__ b1, const float* __restrict__ w2,
    const float* __restrict__ b2, float* __restrict__ out) {
    const int lane = threadIdx.x & 63;
    const int wave = threadIdx.x >> 6;
    const int v = blockIdx.x * 4 + wave;
    if (v >= N_NODES) return;

    const size_t loff = (size_t)lane * 4;

    // self-loop term: h'[v] (already dinv[v]*h[v])
    fp32x4 a0 = bf4_to_f4(*(const u16x4*)(h + (size_t)v * HIDDEN + loff));
    fp32x4 a1 = {0,0,0,0}, a2 = {0,0,0,0}, a3 = {0,0,0,0};

    int e0 = row_start[v], e1 = row_start[v + 1];
    for (int e = e0; e < e1; e += 64) {
        int cnt = min(64, e1 - e);
        int s = (lane < cnt) ? adj[e + lane] : 0;
        int i = 0;
        for (; i + 4 <= cnt; i += 4) {
            int s0 = __shfl(s, i,     64);
            int s1 = __shfl(s, i + 1, 64);
            int s2 = __shfl(s, i + 2, 64);
            int s3 = __shfl(s, i + 3, 64);
            u16x4 r0 = *(const u16x4*)(h + (size_t)s0 * HIDDEN + loff);
            u16x4 r1 = *(const u16x4*)(h + (size_t)s1 * HIDDEN + loff);
            u16x4 r2 = *(const u16x4*)(h + (size_t)s2 * HIDDEN + loff);
            u16x4 r3 = *(const u16x4*)(h + (size_t)s3 * HIDDEN + loff);
            a0 += bf4_to_f4(r0);
            a1 += bf4_to_f4(r1);
            a2 += bf4_to_f4(r2);
            a3 += bf4_to_f4(r3);
        }
        for (; i < cnt; i++) {
            int si = __shfl(s, i, 64);
            a0 += bf4_to_f4(*(const u16x4*)(h + (size_t)si * HIDDEN + loff));
        }
    }
    fp32x4 acc = (a0 + a1) + (a2 + a3);

    float dvv = dinv[v];
    fp32x4 bb = *(const fp32x4*)(b1 + loff);
    float hr[4];
    for (int j = 0; j < 4; j++) hr[j] = fmaxf(0.0f, dvv * acc[j] + bb[j]);

    float p0 = 0.f, p1 = 0.f, p2 = 0.f;
    for (int j = 0; j < 4; j++) {
        const float* wr = w2 + (size_t)(lane * 4 + j) * 3;
        p0 += hr[j] * wr[0];
        p1 += hr[j] * wr[1];
        p2 += hr[j] * wr[2];
    }
    for (int off = 32; off > 0; off >>= 1) {
        p0 += __shfl_down(p0, off, 64);
        p1 += __shfl_down(p1, off, 64);
        p2 += __shfl_down(p2, off, 64);
    }
    if (lane == 0) {
        p0 += b2[0]; p1 += b2[1]; p2 += b2[2];
        float m = fmaxf(p0, fmaxf(p1, p2));
        float l = logf(expf(p0 - m) + expf(p1 - m) + expf(p2 - m));
        out[(size_t)v * 3 + 0] = p0 - m - l;
        out[(size_t)v * 3 + 1] = p1 - m - l;
        out[(size_t)v * 3 + 2] = p2 - m - l;
    }
}

extern "C" void kernel_launch(void* const* d_in, const int* in_sizes, int n_in,
                              void* d_out, int out_size, void* d_ws, size_t ws_size,
                              hipStream_t stream) {
    const float* x    = (const float*)d_in[0];
    const int*   ei   = (const int*)d_in[1];      // [2][N_EDGES]
    const float* W1   = (const float*)d_in[2];
    const float* b1   = (const float*)d_in[3];
    const float* W2   = (const float*)d_in[4];
    const float* b2   = (const float*)d_in[5];
    float* out = (float*)d_out;

    const int* src = ei;
    const int* dst = ei + N_EDGES;

    char* ws = (char*)d_ws;
    unsigned short* h_ws = (unsigned short*)(ws + H_OFF);
    int*   adj       = (int*)(ws + ADJ_OFF);
    int*   row_start = (int*)(ws + RS_OFF);
    int*   cursor    = (int*)(ws + CUR_OFF);
    int*   deg       = (int*)(ws + DEG_OFF);
    float* dinv      = (float*)(ws + DINV_OFF);
    short* w1t       = (short*)(ws + W1T_OFF);
    int*   bsum      = (int*)(ws + BSUM_OFF);

    init_kernel<<<(N_NODES + 255) / 256, 256, 0, stream>>>(deg, cursor);
    w1t_kernel<<<(HIDDEN * IN_DIM + 255) / 256, 256, 0, stream>>>(W1, w1t);
    count_kernel<<<(N_EDGES + 255) / 256, 256, 0, stream>>>(dst, deg);
    scan1_kernel<<<N_SBLK, SCAN_B, 0, stream>>>(deg, bsum);
    scan2_kernel<<<1, 512, 0, stream>>>(bsum);
    scan3_kernel<<<N_SBLK, SCAN_B, 0, stream>>>(deg, bsum, row_start, dinv);
    fill_kernel<<<(N_EDGES + 255) / 256, 256, 0, stream>>>(src, dst, row_start, cursor, adj);
    gemm1_kernel<<<dim3((N_NODES + 127) / 128, HIDDEN / 128), 256, 0, stream>>>(x, w1t, dinv, h_ws);
    aggregate_kernel<<<N_NODES / 4, 256, 0, stream>>>(h_ws, adj, row_start, dinv, b1, W2, b2, out);
}

// Round 3
// 753.544 us; speedup vs baseline: 1.0399x; 1.0399x over previous
//
#include <hip/hip_runtime.h>
#include <hip/hip_bf16.h>
#include <math.h>

#define N_NODES 100000
#define N_EDGES 1600000
#define IN_DIM  768
#define HIDDEN  256

#define SCAN_B  256
#define N_SBLK  ((N_NODES + SCAN_B - 1) / SCAN_B)   // 391

// ---- ws layout (bytes), all offsets 16B-aligned ----
#define H_OFF    0ull                  // bf16 h' [N_NODES][HIDDEN]     51,200,000 B
#define ADJ_OFF  51200000ull           // int adj [N_EDGES]              6,400,000 B
#define RS_OFF   57600000ull           // int row_start [N_NODES+1]        400,004 B
#define CUR_OFF  58000016ull           // int cursor [N_NODES]             400,000 B
#define DEG_OFF  58400016ull           // int deg [N_NODES]                400,000 B
#define DINV_OFF 58800016ull           // float dinv [N_NODES]             400,000 B
#define W1T_OFF  59200016ull           // bf16 W1t [HIDDEN][IN_DIM]        393,216 B
#define BSUM_OFF 59593232ull           // int bsum [N_SBLK]                  1,564 B
// total ~59.6 MB

typedef short          bf16x8 __attribute__((ext_vector_type(8)));
typedef float          fp32x4 __attribute__((ext_vector_type(4)));
typedef unsigned short u16x4  __attribute__((ext_vector_type(4)));

__device__ inline short f2bf(float f) {
    union { float f; unsigned u; } c; c.f = f;
    unsigned u = c.u;
    unsigned r = u + 0x7FFFu + ((u >> 16) & 1u);   // RNE
    return (short)(r >> 16);
}

__device__ inline fp32x4 bf4_to_f4(u16x4 v) {
    fp32x4 r;
    for (int j = 0; j < 4; j++) {
        union { unsigned u; float f; } c;
        c.u = ((unsigned)v[j]) << 16;
        r[j] = c.f;
    }
    return r;
}

// async global->LDS, 16B per lane (wave-uniform dest base + lane*16)
__device__ inline void async16(const void* g, void* l) {
    __builtin_amdgcn_global_load_lds(
        (const __attribute__((address_space(1))) unsigned int*)g,
        (__attribute__((address_space(3))) unsigned int*)l,
        16, 0, 0);
}

// ---------------- init: zero deg + cursor ----------------
__global__ void init_kernel(int* __restrict__ deg, int* __restrict__ cursor) {
    int i = blockIdx.x * blockDim.x + threadIdx.x;
    if (i < N_NODES) { deg[i] = 0; cursor[i] = 0; }
}

// ---------------- W1 -> W1t (bf16, [HIDDEN][IN_DIM]) ----------------
__global__ void w1t_kernel(const float* __restrict__ w1, short* __restrict__ w1t) {
    int i = blockIdx.x * blockDim.x + threadIdx.x;
    if (i < HIDDEN * IN_DIM) {
        int n = i / IN_DIM, k = i % IN_DIM;
        w1t[i] = f2bf(w1[(size_t)k * HIDDEN + n]);
    }
}

// ---------------- count in-degree (real edges only) ----------------
__global__ void count_kernel(const int* __restrict__ dst, int* __restrict__ deg) {
    int e = blockIdx.x * blockDim.x + threadIdx.x;
    if (e < N_EDGES) atomicAdd(&deg[dst[e]], 1);
}

// ---------------- scan phase 1: per-block sums ----------------
__global__ __launch_bounds__(SCAN_B) void scan1_kernel(const int* __restrict__ deg,
                                                       int* __restrict__ bsum) {
    int i = blockIdx.x * SCAN_B + threadIdx.x;
    int v = (i < N_NODES) ? deg[i] : 0;
    for (int off = 32; off > 0; off >>= 1) v += __shfl_down(v, off, 64);
    __shared__ int wsum[SCAN_B / 64];
    int lane = threadIdx.x & 63, w = threadIdx.x >> 6;
    if (lane == 0) wsum[w] = v;
    __syncthreads();
    if (threadIdx.x == 0) {
        int s = 0;
        for (int j = 0; j < SCAN_B / 64; j++) s += wsum[j];
        bsum[blockIdx.x] = s;
    }
}

// ---------------- scan phase 2: exclusive-scan the block sums (1 block) ----------------
__global__ __launch_bounds__(512) void scan2_kernel(int* __restrict__ bsum) {
    __shared__ int s[512];
    int tid = threadIdx.x;
    int v = (tid < N_SBLK) ? bsum[tid] : 0;
    s[tid] = v;
    __syncthreads();
    for (int off = 1; off < 512; off <<= 1) {
        int t = (tid >= off) ? s[tid - off] : 0;
        __syncthreads();
        s[tid] += t;
        __syncthreads();
    }
    if (tid < N_SBLK) bsum[tid] = s[tid] - v;   // exclusive
}

// ---------------- scan phase 3: block-local scan + offset; also dinv ----------------
__global__ __launch_bounds__(SCAN_B) void scan3_kernel(const int* __restrict__ deg,
                                                       const int* __restrict__ bsum,
                                                       int* __restrict__ row_start,
                                                       float* __restrict__ dinv) {
    __shared__ int s[SCAN_B];
    int i = blockIdx.x * SCAN_B + threadIdx.x;
    int tid = threadIdx.x;
    int d = (i < N_NODES) ? deg[i] : 0;
    s[tid] = d;
    __syncthreads();
    for (int off = 1; off < SCAN_B; off <<= 1) {
        int t = (tid >= off) ? s[tid - off] : 0;
        __syncthreads();
        s[tid] += t;
        __syncthreads();
    }
    if (i < N_NODES) {
        row_start[i] = bsum[blockIdx.x] + s[tid] - d;   // exclusive
        dinv[i] = rsqrtf((float)(d + 1));               // +1 self loop
        if (i == N_NODES - 1) row_start[N_NODES] = N_EDGES;  // deg sums to N_EDGES
    }
}

// ---------------- fill CSR adjacency (src list grouped by dst) ----------------
__global__ void fill_kernel(const int* __restrict__ src, const int* __restrict__ dst,
                            const int* __restrict__ row_start, int* __restrict__ cursor,
                            int* __restrict__ adj) {
    int e = blockIdx.x * blockDim.x + threadIdx.x;
    if (e < N_EDGES) {
        int d = dst[e];
        int p = row_start[d] + atomicAdd(&cursor[d], 1);
        adj[p] = src[e];
    }
}

// ---------------- GEMM1: h'[r] = bf16(dinv[r] * (x[r] @ W1)) ----------------
// 128x128 tile, BK=32, both LDS tiles bf16 [128][32] (8 KB each, x2 buffers
// = 32 KB total).
//   B: global_load_lds width-16, linear dest, source pre-swizzled.
//   A: reg-staged (fp32 global -> regs -> f2bf -> ds_write_b128), T14 split:
//      issue loads at loop top, convert+write AFTER the MFMA phase, so HBM
//      latency hides under compute. Each A element converted exactly once.
// Swizzle (both A and B, read side and write/source side):
//   16B slot s_mem = s0 ^ ((row>>1)&3)  -> frag reads are 2-way (free).
// One __syncthreads per K-step (drains B-async vmcnt + A ds_writes).
__global__ __launch_bounds__(256) void gemm1_kernel(const float* __restrict__ x,
                                                    const short* __restrict__ w1t,
                                                    const float* __restrict__ dinv,
                                                    unsigned short* __restrict__ h) {
    __shared__ __align__(16) short a_lds[2 * 128 * 32];   // 2 x 8 KB bf16
    __shared__ __align__(16) short b_lds[2 * 128 * 32];   // 2 x 8 KB bf16

    const int tid  = threadIdx.x;
    const int lane = tid & 63;
    const int wave = tid >> 6;
    const int wm = (wave >> 1) * 64;
    const int wn = (wave & 1) * 64;
    const int l15 = lane & 15;
    const int q   = lane >> 4;

    // bijective XCD-chunked swizzle (nwg=1564, 8 XCDs): consecutive logical
    // ids land on the SAME XCD, and the (col0=0,col0=128) pair sharing an A
    // panel is logically adjacent -> A panel read twice from the same L2.
    const int nwg = gridDim.x;                 // 1564
    const int xq = nwg >> 3, xr = nwg & 7;
    const int orig = blockIdx.x;
    const int xcd = orig & 7, idx = orig >> 3;
    const int wgid = (xcd < xr ? xcd * (xq + 1) : xr * (xq + 1) + (xcd - xr) * xq) + idx;
    const int row0 = (wgid >> 1) * 128;
    const int col0 = (wgid & 1) * 128;

    // ---- A staging geometry (reg path) ----
    // thread -> (row ar = tid>>1, k-half kh = tid&1): 16 consecutive floats.
    const int ar = tid >> 1;
    const int kh = tid & 1;
    int garow = row0 + ar;
    if (garow >= N_NODES) garow = N_NODES - 1;   // clamp: OOB rows never stored
    const float* axp = x + (size_t)garow * IN_DIM + kh * 16;
    const int asw  = (ar >> 1) & 3;
    const int aoff0 = ar * 32 + (((kh * 2 + 0) ^ asw) << 3);   // shorts
    const int aoff1 = ar * 32 + (((kh * 2 + 1) ^ asw) << 3);

    // ---- B staging geometry (global_load_lds) ----
    // 512 x 16B chunks per tile; wave w issue i covers chunks (w*2+i)*64+lane.
    // dest chunk cd = row*4 + c; source slot = c ^ ((row>>1)&3).
    const short* bg[2];
    int blo[2];
#pragma unroll
    for (int i = 0; i < 2; i++) {
        int cd = (wave * 2 + i) * 64 + lane;
        int br = cd >> 2;
        int c  = cd & 3;
        bg[i]  = w1t + (size_t)(col0 + br) * IN_DIM + ((c ^ ((br >> 1) & 3)) * 8);
        blo[i] = cd * 16;   // bytes
    }

    fp32x4 acc[4][4];
#pragma unroll
    for (int i = 0; i < 4; i++)
#pragma unroll
        for (int j = 0; j < 4; j++)
#pragma unroll
            for (int r = 0; r < 4; r++) acc[i][j][r] = 0.0f;

#define BSTAGE(buf, k0) do {                                                  \
        char* bb = (char*)(b_lds + (buf) * (128 * 32));                       \
        async16(bg[0] + (k0), bb + blo[0]);                                   \
        async16(bg[1] + (k0), bb + blo[1]);                                   \
    } while (0)

#define AWRITE(buf, v0, v1, v2, v3) do {                                      \
        short* ad = a_lds + (buf) * (128 * 32);                               \
        bf16x8 wv;                                                            \
        wv[0] = f2bf(v0[0]); wv[1] = f2bf(v0[1]);                             \
        wv[2] = f2bf(v0[2]); wv[3] = f2bf(v0[3]);                             \
        wv[4] = f2bf(v1[0]); wv[5] = f2bf(v1[1]);                             \
        wv[6] = f2bf(v1[2]); wv[7] = f2bf(v1[3]);                             \
        *(bf16x8*)(ad + aoff0) = wv;                                          \
        wv[0] = f2bf(v2[0]); wv[1] = f2bf(v2[1]);                             \
        wv[2] = f2bf(v2[2]); wv[3] = f2bf(v2[3]);                             \
        wv[4] = f2bf(v3[0]); wv[5] = f2bf(v3[1]);                             \
        wv[6] = f2bf(v3[2]); wv[7] = f2bf(v3[3]);                             \
        *(bf16x8*)(ad + aoff1) = wv;                                          \
    } while (0)

    // prologue: tile 0
    {
        fp32x4 na0 = *(const fp32x4*)(axp + 0);
        fp32x4 na1 = *(const fp32x4*)(axp + 4);
        fp32x4 na2 = *(const fp32x4*)(axp + 8);
        fp32x4 na3 = *(const fp32x4*)(axp + 12);
        BSTAGE(0, 0);
        AWRITE(0, na0, na1, na2, na3);
        __syncthreads();   // drains A writes (lgkm) + B asyncs (vmcnt)
    }

    const int fsw = q ^ ((l15 >> 1) & 3);   // frag-read slot (const per lane)

    int cur = 0;
    for (int t = 0; t < IN_DIM / 32; ++t) {
        const int kn = (t + 1) * 32;
        const bool more = kn < IN_DIM;
        fp32x4 na0, na1, na2, na3;
        if (more) {
            // issue-early: next A tile into regs, next B tile via async DMA
            na0 = *(const fp32x4*)(axp + kn);
            na1 = *(const fp32x4*)(axp + kn + 4);
            na2 = *(const fp32x4*)(axp + kn + 8);
            na3 = *(const fp32x4*)(axp + kn + 12);
            BSTAGE(cur ^ 1, kn);
        }

        // compute tile t (pure bf16 ds_read + MFMA; loads above stay in flight)
        const short* ac = a_lds + cur * (128 * 32);
        const short* bc = b_lds + cur * (128 * 32);
        bf16x8 af[4], bfr[4];
#pragma unroll
        for (int mt = 0; mt < 4; mt++)
            af[mt] = *(const bf16x8*)(ac + (wm + mt * 16 + l15) * 32 + (fsw << 3));
#pragma unroll
        for (int nt = 0; nt < 4; nt++)
            bfr[nt] = *(const bf16x8*)(bc + (wn + nt * 16 + l15) * 32 + (fsw << 3));
#pragma unroll
        for (int mt = 0; mt < 4; mt++)
#pragma unroll
            for (int nt = 0; nt < 4; nt++)
                acc[mt][nt] = __builtin_amdgcn_mfma_f32_16x16x32_bf16(
                    af[mt], bfr[nt], acc[mt][nt], 0, 0, 0);

        // write-late: convert next A tile and commit to the other buffer.
        // Safe without an extra barrier: buf cur^1 was last READ in step t-1,
        // whose reads were ordered before the step-(t-1) __syncthreads.
        if (more) AWRITE(cur ^ 1, na0, na1, na2, na3);

        __syncthreads();   // B asyncs + A writes for tile t+1 resident
        cur ^= 1;
    }
#undef BSTAGE
#undef AWRITE

    // epilogue: h'[row][col] = bf16(dinv[row] * acc)
    float dv[4][4];
#pragma unroll
    for (int mt = 0; mt < 4; mt++)
#pragma unroll
        for (int r = 0; r < 4; r++) {
            int row = row0 + wm + mt * 16 + q * 4 + r;
            dv[mt][r] = (row < N_NODES) ? dinv[row] : 0.0f;
        }
#pragma unroll
    for (int mt = 0; mt < 4; mt++) {
#pragma unroll
        for (int nt = 0; nt < 4; nt++) {
            int col = col0 + wn + nt * 16 + l15;
#pragma unroll
            for (int r = 0; r < 4; r++) {
                int row = row0 + wm + mt * 16 + q * 4 + r;
                if (row < N_NODES)
                    h[(size_t)row * HIDDEN + col] =
                        (unsigned short)f2bf(dv[mt][r] * acc[mt][nt][r]);
            }
        }
    }
}

// ---------------- aggregate + bias + relu + W2 + log_softmax ----------------
// one wave per dst node; lane holds 4 of the 256 hidden channels (bf16 h').
// edge loop unrolled x4 with 4 accumulators -> 4 gathers in flight.
__global__ __launch_bounds__(256) void aggregate_kernel(
    const unsigned short* __restrict__ h, const int* __restrict__ adj,
    const int* __restrict__ row_start, const float* __restrict__ dinv,
    const float* __restrict__ b1, const float* __restrict__ w2,
    const float* __restrict__ b2, float* __restrict__ out) {
    const int lane = threadIdx.x & 63;
    const int wave = threadIdx.x >> 6;
    const int v = blockIdx.x * 4 + wave;
    if (v >= N_NODES) return;

    const size_t loff = (size_t)lane * 4;

    // self-loop term: h'[v] (already dinv[v]*h[v])
    fp32x4 a0 = bf4_to_f4(*(const u16x4*)(h + (size_t)v * HIDDEN + loff));
    fp32x4 a1 = {0,0,0,0}, a2 = {0,0,0,0}, a3 = {0,0,0,0};

    int e0 = row_start[v], e1 = row_start[v + 1];
    for (int e = e0; e < e1; e += 64) {
        int cnt = min(64, e1 - e);
        int s = (lane < cnt) ? adj[e + lane] : 0;
        int i = 0;
        for (; i + 4 <= cnt; i += 4) {
            int s0 = __shfl(s, i,     64);
            int s1 = __shfl(s, i + 1, 64);
            int s2 = __shfl(s, i + 2, 64);
            int s3 = __shfl(s, i + 3, 64);
            u16x4 r0 = *(const u16x4*)(h + (size_t)s0 * HIDDEN + loff);
            u16x4 r1 = *(const u16x4*)(h + (size_t)s1 * HIDDEN + loff);
            u16x4 r2 = *(const u16x4*)(h + (size_t)s2 * HIDDEN + loff);
            u16x4 r3 = *(const u16x4*)(h + (size_t)s3 * HIDDEN + loff);
            a0 += bf4_to_f4(r0);
            a1 += bf4_to_f4(r1);
            a2 += bf4_to_f4(r2);
            a3 += bf4_to_f4(r3);
        }
        for (; i < cnt; i++) {
            int si = __shfl(s, i, 64);
            a0 += bf4_to_f4(*(const u16x4*)(h + (size_t)si * HIDDEN + loff));
        }
    }
    fp32x4 acc = (a0 + a1) + (a2 + a3);

    float dvv = dinv[v];
    fp32x4 bb = *(const fp32x4*)(b1 + loff);
    float hr[4];
    for (int j = 0; j < 4; j++) hr[j] = fmaxf(0.0f, dvv * acc[j] + bb[j]);

    float p0 = 0.f, p1 = 0.f, p2 = 0.f;
    for (int j = 0; j < 4; j++) {
        const float* wr = w2 + (size_t)(lane * 4 + j) * 3;
        p0 += hr[j] * wr[0];
        p1 += hr[j] * wr[1];
        p2 += hr[j] * wr[2];
    }
    for (int off = 32; off > 0; off >>= 1) {
        p0 += __shfl_down(p0, off, 64);
        p1 += __shfl_down(p1, off, 64);
        p2 += __shfl_down(p2, off, 64);
    }
    if (lane == 0) {
        p0 += b2[0]; p1 += b2[1]; p2 += b2[2];
        float m = fmaxf(p0, fmaxf(p1, p2));
        float l = logf(expf(p0 - m) + expf(p1 - m) + expf(p2 - m));
        out[(size_t)v * 3 + 0] = p0 - m - l;
        out[(size_t)v * 3 + 1] = p1 - m - l;
        out[(size_t)v * 3 + 2] = p2 - m - l;
    }
}

extern "C" void kernel_launch(void* const* d_in, const int* in_sizes, int n_in,
                              void* d_out, int out_size, void* d_ws, size_t ws_size,
                              hipStream_t stream) {
    const float* x    = (const float*)d_in[0];
    const int*   ei   = (const int*)d_in[1];      // [2][N_EDGES]
    const float* W1   = (const float*)d_in[2];
    const float* b1   = (const float*)d_in[3];
    const float* W2   = (const float*)d_in[4];
    const float* b2   = (const float*)d_in[5];
    float* out = (float*)d_out;

    const int* src = ei;
    const int* dst = ei + N_EDGES;

    char* ws = (char*)d_ws;
    unsigned short* h_ws = (unsigned short*)(ws + H_OFF);
    int*   adj       = (int*)(ws + ADJ_OFF);
    int*   row_start = (int*)(ws + RS_OFF);
    int*   cursor    = (int*)(ws + CUR_OFF);
    int*   deg       = (int*)(ws + DEG_OFF);
    float* dinv      = (float*)(ws + DINV_OFF);
    short* w1t       = (short*)(ws + W1T_OFF);
    int*   bsum      = (int*)(ws + BSUM_OFF);

    init_kernel<<<(N_NODES + 255) / 256, 256, 0, stream>>>(deg, cursor);
    w1t_kernel<<<(HIDDEN * IN_DIM + 255) / 256, 256, 0, stream>>>(W1, w1t);
    count_kernel<<<(N_EDGES + 255) / 256, 256, 0, stream>>>(dst, deg);
    scan1_kernel<<<N_SBLK, SCAN_B, 0, stream>>>(deg, bsum);
    scan2_kernel<<<1, 512, 0, stream>>>(bsum);
    scan3_kernel<<<N_SBLK, SCAN_B, 0, stream>>>(deg, bsum, row_start, dinv);
    fill_kernel<<<(N_EDGES + 255) / 256, 256, 0, stream>>>(src, dst, row_start, cursor, adj);
    gemm1_kernel<<<(N_NODES + 127) / 128 * 2, 256, 0, stream>>>(x, w1t, dinv, h_ws);
    aggregate_kernel<<<N_NODES / 4, 256, 0, stream>>>(h_ws, adj, row_start, dinv, b1, W2, b2, out);
}

// Round 4
// 725.484 us; speedup vs baseline: 1.0801x; 1.0387x over previous
//
#include <hip/hip_runtime.h>
#include <hip/hip_bf16.h>
#include <math.h>

#define N_NODES 100000
#define N_EDGES 1600000
#define IN_DIM  768
#define HIDDEN  256

#define SCAN_B  256
#define N_SBLK  ((N_NODES + SCAN_B - 1) / SCAN_B)   // 391

// ---- ws layout (bytes), all offsets 16B-aligned ----
#define H_OFF    0ull                  // bf16 h' [N_NODES][HIDDEN]     51,200,000 B
#define ADJ_OFF  51200000ull           // int adj [N_EDGES]              6,400,000 B
#define RS_OFF   57600000ull           // int row_start [N_NODES+1]        400,004 B
#define CUR_OFF  58000016ull           // int cursor [N_NODES]             400,000 B
#define DEG_OFF  58400016ull           // int deg [N_NODES]                400,000 B
#define DINV_OFF 58800016ull           // float dinv [N_NODES]             400,000 B
#define W1T_OFF  59200016ull           // bf16 W1t [HIDDEN][IN_DIM]        393,216 B
#define BSUM_OFF 59593232ull           // int bsum [N_SBLK]                  1,564 B
// total ~59.6 MB

typedef short          bf16x8 __attribute__((ext_vector_type(8)));
typedef float          fp32x4 __attribute__((ext_vector_type(4)));
typedef unsigned short u16x4  __attribute__((ext_vector_type(4)));

__device__ inline short f2bf(float f) {
    union { float f; unsigned u; } c; c.f = f;
    unsigned u = c.u;
    unsigned r = u + 0x7FFFu + ((u >> 16) & 1u);   // RNE
    return (short)(r >> 16);
}

__device__ inline fp32x4 bf4_to_f4(u16x4 v) {
    fp32x4 r;
    for (int j = 0; j < 4; j++) {
        union { unsigned u; float f; } c;
        c.u = ((unsigned)v[j]) << 16;
        r[j] = c.f;
    }
    return r;
}

// async global->LDS, 16B per lane (wave-uniform dest base + lane*16)
__device__ inline void async16(const void* g, void* l) {
    __builtin_amdgcn_global_load_lds(
        (const __attribute__((address_space(1))) unsigned int*)g,
        (__attribute__((address_space(3))) unsigned int*)l,
        16, 0, 0);
}

// ---------------- init: zero deg + cursor ----------------
__global__ void init_kernel(int* __restrict__ deg, int* __restrict__ cursor) {
    int i = blockIdx.x * blockDim.x + threadIdx.x;
    if (i < N_NODES) { deg[i] = 0; cursor[i] = 0; }
}

// ---------------- W1 -> W1t (bf16, [HIDDEN][IN_DIM]) ----------------
__global__ void w1t_kernel(const float* __restrict__ w1, short* __restrict__ w1t) {
    int i = blockIdx.x * blockDim.x + threadIdx.x;
    if (i < HIDDEN * IN_DIM) {
        int n = i / IN_DIM, k = i % IN_DIM;
        w1t[i] = f2bf(w1[(size_t)k * HIDDEN + n]);
    }
}

// ---------------- count in-degree (real edges only) ----------------
__global__ void count_kernel(const int* __restrict__ dst, int* __restrict__ deg) {
    int e = blockIdx.x * blockDim.x + threadIdx.x;
    if (e < N_EDGES) atomicAdd(&deg[dst[e]], 1);
}

// ---------------- scan phase 1: per-block sums ----------------
__global__ __launch_bounds__(SCAN_B) void scan1_kernel(const int* __restrict__ deg,
                                                       int* __restrict__ bsum) {
    int i = blockIdx.x * SCAN_B + threadIdx.x;
    int v = (i < N_NODES) ? deg[i] : 0;
    for (int off = 32; off > 0; off >>= 1) v += __shfl_down(v, off, 64);
    __shared__ int wsum[SCAN_B / 64];
    int lane = threadIdx.x & 63, w = threadIdx.x >> 6;
    if (lane == 0) wsum[w] = v;
    __syncthreads();
    if (threadIdx.x == 0) {
        int s = 0;
        for (int j = 0; j < SCAN_B / 64; j++) s += wsum[j];
        bsum[blockIdx.x] = s;
    }
}

// ---------------- scan phase 2: exclusive-scan the block sums (1 block) ----------------
__global__ __launch_bounds__(512) void scan2_kernel(int* __restrict__ bsum) {
    __shared__ int s[512];
    int tid = threadIdx.x;
    int v = (tid < N_SBLK) ? bsum[tid] : 0;
    s[tid] = v;
    __syncthreads();
    for (int off = 1; off < 512; off <<= 1) {
        int t = (tid >= off) ? s[tid - off] : 0;
        __syncthreads();
        s[tid] += t;
        __syncthreads();
    }
    if (tid < N_SBLK) bsum[tid] = s[tid] - v;   // exclusive
}

// ---------------- scan phase 3: block-local scan + offset; also dinv ----------------
__global__ __launch_bounds__(SCAN_B) void scan3_kernel(const int* __restrict__ deg,
                                                       const int* __restrict__ bsum,
                                                       int* __restrict__ row_start,
                                                       float* __restrict__ dinv) {
    __shared__ int s[SCAN_B];
    int i = blockIdx.x * SCAN_B + threadIdx.x;
    int tid = threadIdx.x;
    int d = (i < N_NODES) ? deg[i] : 0;
    s[tid] = d;
    __syncthreads();
    for (int off = 1; off < SCAN_B; off <<= 1) {
        int t = (tid >= off) ? s[tid - off] : 0;
        __syncthreads();
        s[tid] += t;
        __syncthreads();
    }
    if (i < N_NODES) {
        row_start[i] = bsum[blockIdx.x] + s[tid] - d;   // exclusive
        dinv[i] = rsqrtf((float)(d + 1));               // +1 self loop
        if (i == N_NODES - 1) row_start[N_NODES] = N_EDGES;  // deg sums to N_EDGES
    }
}

// ---------------- fill CSR adjacency (src list grouped by dst) ----------------
__global__ void fill_kernel(const int* __restrict__ src, const int* __restrict__ dst,
                            const int* __restrict__ row_start, int* __restrict__ cursor,
                            int* __restrict__ adj) {
    int e = blockIdx.x * blockDim.x + threadIdx.x;
    if (e < N_EDGES) {
        int d = dst[e];
        int p = row_start[d] + atomicAdd(&cursor[d], 1);
        adj[p] = src[e];
    }
}

// ---------------- GEMM1: h'[r] = bf16(dinv[r] * (x[r] @ W1)) ----------------
// Block tile 128 rows x 256 cols (FULL HIDDEN) so the fp32 A panel is issued
// exactly ONCE (previously two col-blocks each read it: 923 MB issued ->
// 614 MB, kernel was at ~85% of the per-CU load-issue ceiling).
// 512 threads = 8 waves (2 row x 4 col), wave tile 64x64, BK=32.
//   B: global_load_lds width-16, linear dest, source pre-swizzled (2/wave/step).
//   A: reg-staged (fp32 -> regs -> f2bf -> ds_write_b128), T14 split: loads
//      issued at loop top, convert+write AFTER MFMA. 8 floats/thread/step.
// Swizzle both tiles: 16B slot s_mem = s0 ^ ((row>>1)&3) -> 2-way free reads.
// One __syncthreads per K-step. LDS = 2x8KB (A) + 2x16KB (B) = 48 KB.
__global__ __launch_bounds__(512) void gemm1_kernel(const float* __restrict__ x,
                                                    const short* __restrict__ w1t,
                                                    const float* __restrict__ dinv,
                                                    unsigned short* __restrict__ h) {
    __shared__ __align__(16) short a_lds[2 * 128 * 32];   // 2 x 8 KB bf16
    __shared__ __align__(16) short b_lds[2 * 256 * 32];   // 2 x 16 KB bf16

    const int tid  = threadIdx.x;
    const int lane = tid & 63;
    const int wave = tid >> 6;          // 0..7
    const int wm = (wave >> 2) * 64;    // 0 or 64
    const int wn = (wave & 3) * 64;     // 0,64,128,192
    const int l15 = lane & 15;
    const int q   = lane >> 4;

    // bijective XCD-chunked swizzle (nwg=782, 8 XCDs): consecutive logical
    // row-panels land on the same XCD's L2 (W1t is L2-resident everywhere).
    const int nwg = gridDim.x;                 // 782
    const int xq = nwg >> 3, xr = nwg & 7;
    const int orig = blockIdx.x;
    const int xcd = orig & 7, idx = orig >> 3;
    const int wgid = (xcd < xr ? xcd * (xq + 1) : xr * (xq + 1) + (xcd - xr) * xq) + idx;
    const int row0 = wgid * 128;

    // ---- A staging geometry (reg path) ----
    // thread -> (row ar = tid>>2, k-quarter kq = tid&3): 8 consecutive floats.
    const int ar = tid >> 2;
    const int kq = tid & 3;
    int garow = row0 + ar;
    if (garow >= N_NODES) garow = N_NODES - 1;   // clamp: OOB rows never stored
    const float* axp = x + (size_t)garow * IN_DIM + kq * 8;
    const int asw  = (ar >> 1) & 3;
    const int aoff = ar * 32 + ((kq ^ asw) << 3);   // shorts

    // ---- B staging geometry (global_load_lds) ----
    // 1024 x 16B chunks per tile; wave w issue i (i<2) covers chunks
    // (w*2+i)*64+lane. dest chunk cd = row*4 + c; source slot = c ^ ((row>>1)&3).
    const short* bg[2];
    int blo[2];
#pragma unroll
    for (int i = 0; i < 2; i++) {
        int cd = (wave * 2 + i) * 64 + lane;
        int br = cd >> 2;          // 0..255
        int c  = cd & 3;
        bg[i]  = w1t + (size_t)br * IN_DIM + ((c ^ ((br >> 1) & 3)) * 8);
        blo[i] = cd * 16;   // bytes
    }

    fp32x4 acc[4][4];
#pragma unroll
    for (int i = 0; i < 4; i++)
#pragma unroll
        for (int j = 0; j < 4; j++)
#pragma unroll
            for (int r = 0; r < 4; r++) acc[i][j][r] = 0.0f;

#define BSTAGE(buf, k0) do {                                                  \
        char* bb = (char*)(b_lds + (buf) * (256 * 32));                       \
        async16(bg[0] + (k0), bb + blo[0]);                                   \
        async16(bg[1] + (k0), bb + blo[1]);                                   \
    } while (0)

#define AWRITE(buf, v0, v1) do {                                              \
        short* ad = a_lds + (buf) * (128 * 32);                               \
        bf16x8 wv;                                                            \
        wv[0] = f2bf(v0[0]); wv[1] = f2bf(v0[1]);                             \
        wv[2] = f2bf(v0[2]); wv[3] = f2bf(v0[3]);                             \
        wv[4] = f2bf(v1[0]); wv[5] = f2bf(v1[1]);                             \
        wv[6] = f2bf(v1[2]); wv[7] = f2bf(v1[3]);                             \
        *(bf16x8*)(ad + aoff) = wv;                                           \
    } while (0)

    // prologue: tile 0
    {
        fp32x4 na0 = *(const fp32x4*)(axp + 0);
        fp32x4 na1 = *(const fp32x4*)(axp + 4);
        BSTAGE(0, 0);
        AWRITE(0, na0, na1);
        __syncthreads();   // drains A writes (lgkm) + B asyncs (vmcnt)
    }

    const int fsw = q ^ ((l15 >> 1) & 3);   // frag-read slot (const per lane)

    int cur = 0;
    for (int t = 0; t < IN_DIM / 32; ++t) {
        const int kn = (t + 1) * 32;
        const bool more = kn < IN_DIM;
        fp32x4 na0, na1;
        if (more) {
            // issue-early: next A tile into regs, next B tile via async DMA
            na0 = *(const fp32x4*)(axp + kn);
            na1 = *(const fp32x4*)(axp + kn + 4);
            BSTAGE(cur ^ 1, kn);
        }

        // compute tile t (pure bf16 ds_read + MFMA; loads above stay in flight)
        const short* ac = a_lds + cur * (128 * 32);
        const short* bc = b_lds + cur * (256 * 32);
        bf16x8 af[4], bfr[4];
#pragma unroll
        for (int mt = 0; mt < 4; mt++)
            af[mt] = *(const bf16x8*)(ac + (wm + mt * 16 + l15) * 32 + (fsw << 3));
#pragma unroll
        for (int nt = 0; nt < 4; nt++)
            bfr[nt] = *(const bf16x8*)(bc + (wn + nt * 16 + l15) * 32 + (fsw << 3));
#pragma unroll
        for (int mt = 0; mt < 4; mt++)
#pragma unroll
            for (int nt = 0; nt < 4; nt++)
                acc[mt][nt] = __builtin_amdgcn_mfma_f32_16x16x32_bf16(
                    af[mt], bfr[nt], acc[mt][nt], 0, 0, 0);

        // write-late: convert next A tile and commit to the other buffer.
        // Safe without an extra barrier: buf cur^1 was last READ in step t-1,
        // whose reads were ordered before the step-(t-1) __syncthreads.
        if (more) AWRITE(cur ^ 1, na0, na1);

        __syncthreads();   // B asyncs + A writes for tile t+1 resident
        cur ^= 1;
    }
#undef BSTAGE
#undef AWRITE

    // epilogue: h'[row][col] = bf16(dinv[row] * acc)
    float dv[4][4];
#pragma unroll
    for (int mt = 0; mt < 4; mt++)
#pragma unroll
        for (int r = 0; r < 4; r++) {
            int row = row0 + wm + mt * 16 + q * 4 + r;
            dv[mt][r] = (row < N_NODES) ? dinv[row] : 0.0f;
        }
#pragma unroll
    for (int mt = 0; mt < 4; mt++) {
#pragma unroll
        for (int nt = 0; nt < 4; nt++) {
            int col = wn + nt * 16 + l15;
#pragma unroll
            for (int r = 0; r < 4; r++) {
                int row = row0 + wm + mt * 16 + q * 4 + r;
                if (row < N_NODES)
                    h[(size_t)row * HIDDEN + col] =
                        (unsigned short)f2bf(dv[mt][r] * acc[mt][nt][r]);
            }
        }
    }
}

// ---------------- aggregate + bias + relu + W2 + log_softmax ----------------
// one wave per dst node; lane holds 4 of the 256 hidden channels (bf16 h').
// edge loop unrolled x4 with 4 accumulators -> 4 gathers in flight.
__global__ __launch_bounds__(256) void aggregate_kernel(
    const unsigned short* __restrict__ h, const int* __restrict__ adj,
    const int* __restrict__ row_start, const float* __restrict__ dinv,
    const float* __restrict__ b1, const float* __restrict__ w2,
    const float* __restrict__ b2, float* __restrict__ out) {
    const int lane = threadIdx.x & 63;
    const int wave = threadIdx.x >> 6;
    const int v = blockIdx.x * 4 + wave;
    if (v >= N_NODES) return;

    const size_t loff = (size_t)lane * 4;

    // self-loop term: h'[v] (already dinv[v]*h[v])
    fp32x4 a0 = bf4_to_f4(*(const u16x4*)(h + (size_t)v * HIDDEN + loff));
    fp32x4 a1 = {0,0,0,0}, a2 = {0,0,0,0}, a3 = {0,0,0,0};

    int e0 = row_start[v], e1 = row_start[v + 1];
    for (int e = e0; e < e1; e += 64) {
        int cnt = min(64, e1 - e);
        int s = (lane < cnt) ? adj[e + lane] : 0;
        int i = 0;
        for (; i + 4 <= cnt; i += 4) {
            int s0 = __shfl(s, i,     64);
            int s1 = __shfl(s, i + 1, 64);
            int s2 = __shfl(s, i + 2, 64);
            int s3 = __shfl(s, i + 3, 64);
            u16x4 r0 = *(const u16x4*)(h + (size_t)s0 * HIDDEN + loff);
            u16x4 r1 = *(const u16x4*)(h + (size_t)s1 * HIDDEN + loff);
            u16x4 r2 = *(const u16x4*)(h + (size_t)s2 * HIDDEN + loff);
            u16x4 r3 = *(const u16x4*)(h + (size_t)s3 * HIDDEN + loff);
            a0 += bf4_to_f4(r0);
            a1 += bf4_to_f4(r1);
            a2 += bf4_to_f4(r2);
            a3 += bf4_to_f4(r3);
        }
        for (; i < cnt; i++) {
            int si = __shfl(s, i, 64);
            a0 += bf4_to_f4(*(const u16x4*)(h + (size_t)si * HIDDEN + loff));
        }
    }
    fp32x4 acc = (a0 + a1) + (a2 + a3);

    float dvv = dinv[v];
    fp32x4 bb = *(const fp32x4*)(b1 + loff);
    float hr[4];
    for (int j = 0; j < 4; j++) hr[j] = fmaxf(0.0f, dvv * acc[j] + bb[j]);

    float p0 = 0.f, p1 = 0.f, p2 = 0.f;
    for (int j = 0; j < 4; j++) {
        const float* wr = w2 + (size_t)(lane * 4 + j) * 3;
        p0 += hr[j] * wr[0];
        p1 += hr[j] * wr[1];
        p2 += hr[j] * wr[2];
    }
    for (int off = 32; off > 0; off >>= 1) {
        p0 += __shfl_down(p0, off, 64);
        p1 += __shfl_down(p1, off, 64);
        p2 += __shfl_down(p2, off, 64);
    }
    if (lane == 0) {
        p0 += b2[0]; p1 += b2[1]; p2 += b2[2];
        float m = fmaxf(p0, fmaxf(p1, p2));
        float l = logf(expf(p0 - m) + expf(p1 - m) + expf(p2 - m));
        out[(size_t)v * 3 + 0] = p0 - m - l;
        out[(size_t)v * 3 + 1] = p1 - m - l;
        out[(size_t)v * 3 + 2] = p2 - m - l;
    }
}

extern "C" void kernel_launch(void* const* d_in, const int* in_sizes, int n_in,
                              void* d_out, int out_size, void* d_ws, size_t ws_size,
                              hipStream_t stream) {
    const float* x    = (const float*)d_in[0];
    const int*   ei   = (const int*)d_in[1];      // [2][N_EDGES]
    const float* W1   = (const float*)d_in[2];
    const float* b1   = (const float*)d_in[3];
    const float* W2   = (const float*)d_in[4];
    const float* b2   = (const float*)d_in[5];
    float* out = (float*)d_out;

    const int* src = ei;
    const int* dst = ei + N_EDGES;

    char* ws = (char*)d_ws;
    unsigned short* h_ws = (unsigned short*)(ws + H_OFF);
    int*   adj       = (int*)(ws + ADJ_OFF);
    int*   row_start = (int*)(ws + RS_OFF);
    int*   cursor    = (int*)(ws + CUR_OFF);
    int*   deg       = (int*)(ws + DEG_OFF);
    float* dinv      = (float*)(ws + DINV_OFF);
    short* w1t       = (short*)(ws + W1T_OFF);
    int*   bsum      = (int*)(ws + BSUM_OFF);

    init_kernel<<<(N_NODES + 255) / 256, 256, 0, stream>>>(deg, cursor);
    w1t_kernel<<<(HIDDEN * IN_DIM + 255) / 256, 256, 0, stream>>>(W1, w1t);
    count_kernel<<<(N_EDGES + 255) / 256, 256, 0, stream>>>(dst, deg);
    scan1_kernel<<<N_SBLK, SCAN_B, 0, stream>>>(deg, bsum);
    scan2_kernel<<<1, 512, 0, stream>>>(bsum);
    scan3_kernel<<<N_SBLK, SCAN_B, 0, stream>>>(deg, bsum, row_start, dinv);
    fill_kernel<<<(N_EDGES + 255) / 256, 256, 0, stream>>>(src, dst, row_start, cursor, adj);
    gemm1_kernel<<<(N_NODES + 127) / 128, 512, 0, stream>>>(x, w1t, dinv, h_ws);
    aggregate_kernel<<<N_NODES / 4, 256, 0, stream>>>(h_ws, adj, row_start, dinv, b1, W2, b2, out);
}